// Round 9
// baseline (270.136 us; speedup 1.0000x reference)
//
#include <hip/hip_runtime.h>

// ComHG graph attention: N=50000, E=1.6M, DIN=128, DOUT=256, DA=32
// Round 15 (part scatter fix; revert failed coop mega-kernel):
//  - R8 coop launch never ran under graph capture (absmax == max|ref|) ->
//    back to the proven R7 multi-dispatch pipeline.
//  - Top-down accounting: boundaries ~1-2us (R2->R3), so R7's 170us
//    non-node = reset(~30) + wconv(4) + gemm(15) + super(~115). proj is
//    ~15us of streaming -> part ~= 100us, >> its 35MB logical traffic.
//    Cause: scatter phase writes 8B per lane to ~60 DIFFERENT bucket runs
//    per wave -> ~1 line transaction (128B RFO+WB, cross-XCD ping-pong)
//    per EDGE ~= 400MB hidden line traffic.
//  - part v2: counting-sort the 8192-edge chunk in LDS first (se[] 64KB,
//    bucket id packed in bits 22..31), THEN write ibuf in LDS order:
//    consecutive lanes -> consecutive addresses within each ~84B run
//    -> ~6 line-touches/wave (10x fewer). part is 196 blocks (0.77/CU),
//    so its 73KB LDS / 2 blocks-per-CU cap costs nothing.
//  - super split back into part + proj (union LDS would cap proj at 2/CU);
//    proj builds wrct per-block in LDS from L2-hot Wr/Wc (no dependency).
//  - node + gemm verbatim R7 (controls: 85us / 229MB / 2.9TB/s).
// Pipeline (5 dispatches):
//   K0 wconv: Wxt(bf16 [n][k]); bcursor[b]=b*BCAP
//   K1 part:  per 8192-edge block: LDS hist+scan -> LDS counting sort ->
//             coalesced run-writes of ibuf{rowlocal<<16|col, adj}
//   K2 proj:  MFMA: a_row(f32)=x@W_row*rsqrt(DA); a_colh=bf16(x@W_col);
//             xh=bf16(x); wrct built in LDS per block
//   K3 node:  per-bucket LDS sort + fused logits/softmax/SpMM -> feath(bf16)
//   K4 gemm:  out = feath @ Wxt^T + b_x   (MFMA bf16, f32 acc)
// (global-max shift dropped: cancels in p/deg up to 1e-15 eps)

#define DIN   128
#define DOUT  256
#define DA    32
#define SLOPE 0.2f
#define RSQRT_DA 0.17677669529663687f   // 1/sqrt(32)
#define BSH   6                         // 64 nodes per bucket
#define BCAP  2560                      // bucket capacity: mean 2048, +11sigma
#define CSTRIDE 32                      // bcursor padding: 1 counter / 128B
#define NBMAX 800                       // LDS sizing; nb = ceil(n/64) = 782
#define PB_CHUNK 8192
#define NU    5                         // BCAP/512 staging iters (node)

typedef unsigned int uint;
typedef unsigned short ushort;
typedef __attribute__((ext_vector_type(8))) short bf16x8;
typedef __attribute__((ext_vector_type(4))) float f32x4;

static __device__ __forceinline__ ushort f2bf(float f) {
  const uint u = __float_as_uint(f);
  return (ushort)((u + 0x7fffu + ((u >> 16) & 1u)) >> 16);
}

// ---------------- K0: Wxt prep + bucket cursor init ----------------
// blocks 0..15 : Wx (f32 [k][n=256]) -> Wxt (bf16 [n][k])
// block  16    : bcursor[b*CSTRIDE] = b*BCAP
__global__ __launch_bounds__(256) void wconv_kernel(
    const float* __restrict__ Wx, ushort* __restrict__ wxt,
    int* __restrict__ bcursor, int nb) {
  __shared__ ushort s[16][DIN];
  const int t = threadIdx.x;
  const int b = blockIdx.x;
  if (b < 16) {
    const int c0 = b * 16;
#pragma unroll
    for (int u = 0; u < 8; ++u) {
      const int k = u * 16 + (t >> 4);
      s[t & 15][k] = f2bf(Wx[(size_t)k * DOUT + c0 + (t & 15)]);
    }
    __syncthreads();
    const int c = t >> 4;          // 0..15
    const int kk = (t & 15) * 8;   // 0..120
    *(uint4*)(wxt + (size_t)(c0 + c) * DIN + kk) = *(const uint4*)&s[c][kk];
  } else {
    for (int i = t; i < nb; i += 256) bcursor[i * CSTRIDE] = i * BCAP;
  }
}

// ---------------- K1: partition with LDS counting sort ----------------
// Per 8192-edge chunk: hist -> scan -> global reserve -> LDS sort (bucket
// id packed at bits 22..31) -> write ibuf in LDS order (coalesced runs).
__global__ __launch_bounds__(512) void part_kernel(
    const int* __restrict__ row, const int* __restrict__ col,
    const float* __restrict__ adj, int* __restrict__ bcursor,
    int2* __restrict__ ibuf, int nb, int E) {
  __shared__ int2 se[PB_CHUNK];      // 64 KB staged sorted edges
  __shared__ int  hist[NBMAX];       // 3.2 KB
  __shared__ int  lscan[NBMAX];      // 3.2 KB
  __shared__ int  gbase[NBMAX];      // 3.2 KB
  const int t = threadIdx.x;
  const int e0 = blockIdx.x * PB_CHUNK;
  int myrow[PB_CHUNK / 512];
  for (int b = t; b < nb; b += 512) hist[b] = 0;
  __syncthreads();
#pragma unroll
  for (int u = 0; u < PB_CHUNK / 512; ++u) {
    const int e = e0 + u * 512 + t;
    myrow[u] = (e < E) ? row[e] : -1;
    if (myrow[u] >= 0) atomicAdd(&hist[myrow[u] >> BSH], 1);
  }
  __syncthreads();
  if (t < 64) {                      // single-wave chunked exclusive scan
    int running = 0;
    for (int base = 0; base < nb; base += 64) {
      const int idx = base + t;
      const int v = (idx < nb) ? hist[idx] : 0;
      int inc = v;
#pragma unroll
      for (int ofs = 1; ofs < 64; ofs <<= 1) {
        const int o = __shfl_up(inc, ofs, 64);
        if (t >= ofs) inc += o;
      }
      if (idx < nb) lscan[idx] = running + inc - v;
      running += __shfl(inc, 63, 64);
    }
  }
  __syncthreads();
  for (int b = t; b < nb; b += 512) {
    const int c = hist[b];
    gbase[b] = c ? atomicAdd(&bcursor[b * CSTRIDE], c) : 0;
    hist[b] = 0;                     // reuse as rank counter
  }
  __syncthreads();
#pragma unroll
  for (int u = 0; u < PB_CHUNK / 512; ++u) {
    const int e = e0 + u * 512 + t;
    if (myrow[u] >= 0) {
      const int b = myrow[u] >> BSH;
      const int pos = lscan[b] + atomicAdd(&hist[b], 1);
      se[pos] = make_int2((b << 22) | ((myrow[u] & 63) << 16) | col[e],
                          __float_as_int(adj[e]));
    }
  }
  __syncthreads();
  const int cnt_total = min(PB_CHUNK, E - e0);
#pragma unroll
  for (int u = 0; u < PB_CHUNK / 512; ++u) {
    const int el = u * 512 + t;
    if (el < cnt_total) {
      const int2 v = se[el];
      const int b = (int)((uint)v.x >> 22);
      ibuf[gbase[b] + (el - lscan[b])] = make_int2(v.x & 0x3fffff, v.y);
    }
  }
}

// ---------------- K2: MFMA projections + bf16 x copy ----------------
// 32 nodes/block @512thr. wrct (64x128 bf16) built in LDS from L2-hot
// Wr/Wc (32KB f32) — no cross-dispatch dependency.
__global__ __launch_bounds__(512) void proj_kernel(
    const float* __restrict__ x, const float* __restrict__ Wr,
    const float* __restrict__ Wc, float* __restrict__ a_row,
    ushort* __restrict__ a_colh, ushort* __restrict__ xh, int n) {
  __shared__ ushort xb[32][136];    // +8 pad: 2-way banks on b128 reads
  __shared__ ushort wrc[64][136];   // +8 pad: 2-way banks on b128 reads
  const int t = threadIdx.x;
  for (int g = t; g < 64 * DIN; g += 512) {   // g = c*128 + k (L1/L2-hot)
    const int c = g >> 7, k = g & 127;
    const float v = (c < DA) ? Wr[(size_t)k * DA + c]
                             : Wc[(size_t)k * DA + (c - DA)];
    wrc[c][k] = f2bf(v);
  }
  const int node0 = blockIdx.x * 32;
  const float4* xg = (const float4*)(x + (size_t)node0 * DIN);
  if (node0 + 32 <= n) {
#pragma unroll
    for (int u = 0; u < 2; ++u) {
      const int f = t + u * 512;               // 0..1023 = node*32 + c4
      const float4 v = xg[f];
      ushort4 h;
      h.x = f2bf(v.x); h.y = f2bf(v.y); h.z = f2bf(v.z); h.w = f2bf(v.w);
      *(ushort4*)&xb[f >> 5][(f & 31) * 4] = h;
      ((ushort4*)(xh + (size_t)node0 * DIN))[f] = h;
    }
  } else {                                     // guarded tail block
#pragma unroll
    for (int u = 0; u < 2; ++u) {
      const int f = t + u * 512;
      const int nd = node0 + (f >> 5);
      float4 v;
      if (nd < n) v = xg[f];
      else { v.x = 0.f; v.y = 0.f; v.z = 0.f; v.w = 0.f; }
      ushort4 h;
      h.x = f2bf(v.x); h.y = f2bf(v.y); h.z = f2bf(v.z); h.w = f2bf(v.w);
      *(ushort4*)&xb[f >> 5][(f & 31) * 4] = h;
      if (nd < n) ((ushort4*)(xh + (size_t)node0 * DIN))[f] = h;
    }
  }
  __syncthreads();

  const int w = t >> 6;
  const int l = t & 63;
  const int lr = l & 15;
  const int lk = (l >> 4) * 8;
  const int h2 = w & 1;          // node half (16 nodes each)
  const int q = w >> 1;          // col quarter (16 of 64 cols)
  f32x4 acc = {0.f, 0.f, 0.f, 0.f};
#pragma unroll
  for (int kk = 0; kk < 4; ++kk) {
    const bf16x8 a = *(const bf16x8*)&xb[h2 * 16 + lr][kk * 32 + lk];
    const bf16x8 bb = *(const bf16x8*)&wrc[q * 16 + lr][kk * 32 + lk];
    acc = __builtin_amdgcn_mfma_f32_16x16x32_bf16(a, bb, acc, 0, 0, 0);
  }
  const int colq = q * 16 + lr;  // 0..63 of [a_row | a_col]
  const int r0 = (l >> 4) * 4;
#pragma unroll
  for (int r = 0; r < 4; ++r) {
    const int node = node0 + h2 * 16 + r0 + r;
    if (node < n) {
      if (colq < DA)
        a_row[(size_t)node * DA + colq] = acc[r] * RSQRT_DA;
      else
        a_colh[(size_t)node * DA + (colq - DA)] = f2bf(acc[r]);
    }
  }
}

// ---------------- K3: per-bucket sort + fused logits/softmax/SpMM ----------
// Block = one 64-node bucket, 512 thr (8 waves). Stage bucket edges to regs,
// LDS hist + single-wave shfl scan + scatter -> sorted eL, then
// 2-nodes-per-wave pair loop (4 pairs/wave): wave = 2 nodes x 32 lanes,
// lane covers 4 feature cols via uint2 xh load.
#define NODE_BODY(J)                                                    \
  {                                                                     \
    const int2 e = spk[w][half][(J)];                                   \
    const float pv = sp[w][half][(J)];                                  \
    const uint2 xv = xh2[(size_t)e.x * 32 + la];                        \
    const float av = __int_as_float(e.y);                               \
    const float f0 = __uint_as_float(xv.x << 16);                       \
    const float f1 = __uint_as_float(xv.x & 0xffff0000u);               \
    const float f2 = __uint_as_float(xv.y << 16);                       \
    const float f3 = __uint_as_float(xv.y & 0xffff0000u);               \
    aa0 += av * f0; aa1 += av * f1; aa2 += av * f2; aa3 += av * f3;     \
    ap0 += pv * f0; ap1 += pv * f1; ap2 += pv * f2; ap3 += pv * f3;     \
    deg += pv;                                                          \
  }

__global__ __launch_bounds__(512) void node_kernel(
    const uint* __restrict__ xh, const float* __restrict__ a_row,
    const ushort* __restrict__ a_colh, const int* __restrict__ bcursor,
    const int2* __restrict__ ibuf, ushort* __restrict__ feath, int n) {
  __shared__ int2  eL[BCAP];          // 20 KB sorted {col, adj}
  __shared__ int   cnt[64];
  __shared__ int   excl[65];
  __shared__ int2  spk[8][2][32];
  __shared__ float sp[8][2][32];
  __shared__ float s_ar[8][2][32];
  const int t = threadIdx.x;
  const int b = blockIdx.x;
  const int node0 = b << BSH;
  const int estart = b * BCAP;
  const int ecnt = bcursor[b * CSTRIDE] - estart;

  if (t < 64) cnt[t] = 0;
  __syncthreads();
  int2 myv[NU];
#pragma unroll
  for (int u = 0; u < NU; ++u) {
    const int e = u * 512 + t;
    if (e < ecnt) {
      myv[u] = ibuf[estart + e];
      atomicAdd(&cnt[myv[u].x >> 16], 1);
    }
  }
  __syncthreads();
  if (t < 64) {                        // single-wave inclusive scan (shfl)
    const int v = cnt[t];
    int inc = v;
#pragma unroll
    for (int ofs = 1; ofs < 64; ofs <<= 1) {
      const int o = __shfl_up(inc, ofs, 64);
      if (t >= ofs) inc += o;
    }
    excl[t] = inc - v;                 // exclusive
    if (t == 63) excl[64] = inc;       // == ecnt
    cnt[t] = 0;                        // reuse as rank counter
  }
  __syncthreads();
#pragma unroll
  for (int u = 0; u < NU; ++u) {
    const int e = u * 512 + t;
    if (e < ecnt) {
      const int rl = myv[u].x >> 16;
      const int pos = excl[rl] + atomicAdd(&cnt[rl], 1);
      eL[pos] = make_int2(myv[u].x & 0xffff, myv[u].y);
    }
  }
  __syncthreads();

  const int w = t >> 6;
  const int lane = t & 63;
  const int half = lane >> 5;
  const int la = lane & 31;
  const uint2* xh2 = (const uint2*)xh;

  for (int pp = 0; pp < 4; ++pp) {          // 4 pairs per wave (8 waves)
    const int rl0 = (pp * 8 + w) * 2;       // local row of first node in pair
    const int i = node0 + rl0 + half;
    const int o0 = excl[rl0];
    const int o1 = excl[rl0 + 1];
    const int o2 = excl[rl0 + 2];
    const int d0 = o1 - o0, d1 = o2 - o1;
    const int myoff = half ? o1 : o0;
    const int myd = half ? d1 : d0;
    const int dmax = max(d0, d1);           // wave-uniform
    s_ar[w][half][la] = (i < n) ? a_row[(size_t)i * DA + la] : 0.f;

    float aa0 = 0.f, aa1 = 0.f, aa2 = 0.f, aa3 = 0.f;
    float ap0 = 0.f, ap1 = 0.f, ap2 = 0.f, ap3 = 0.f;
    float deg = 0.f;

    for (int base = 0; base < dmax; base += 32) {
      const int m = myd - base;             // active count for this half
      if (la < m) {
        const int2 e = eL[myoff + base + la];
        spk[w][half][la] = e;
        const uint4* ac = (const uint4*)(a_colh + (size_t)e.x * DA);
        const float* ar = s_ar[w][half];
        float dot = 0.f;
#pragma unroll
        for (int k = 0; k < 4; ++k) {
          const uint4 q = ac[k];
          const float* a = ar + k * 8;
          dot += __uint_as_float(q.x << 16) * a[0] +
                 __uint_as_float(q.x & 0xffff0000u) * a[1] +
                 __uint_as_float(q.y << 16) * a[2] +
                 __uint_as_float(q.y & 0xffff0000u) * a[3] +
                 __uint_as_float(q.z << 16) * a[4] +
                 __uint_as_float(q.z & 0xffff0000u) * a[5] +
                 __uint_as_float(q.w << 16) * a[6] +
                 __uint_as_float(q.w & 0xffff0000u) * a[7];
        }
        const float lg = (dot >= 0.f) ? dot : SLOPE * dot;
        sp[w][half][la] = __expf(lg);       // same-wave RAW, no barrier
      } else {
        spk[w][half][la] = make_int2(0, 0); // col 0, adj 0 -> harmless
        sp[w][half][la] = 0.f;
      }
      const int mmax = min(32, dmax - base);
      int j = 0;
      for (; j + 8 <= mmax; j += 8) {
#pragma unroll
        for (int u = 0; u < 8; ++u) NODE_BODY(j + u)
      }
      for (; j < mmax; ++j) NODE_BODY(j)
    }
    if (i < n) {
      const float inv = 0.5f / (deg + 1e-15f);
      ushort4 h;
      h.x = f2bf(0.5f * aa0 + inv * ap0);
      h.y = f2bf(0.5f * aa1 + inv * ap1);
      h.z = f2bf(0.5f * aa2 + inv * ap2);
      h.w = f2bf(0.5f * aa3 + inv * ap3);
      *(ushort4*)(feath + (size_t)i * DIN + la * 4) = h;
    }
  }
}

// ---------------- K4: MFMA GEMM out = feath @ Wxt^T + b ----------------
__global__ __launch_bounds__(256) void gemm_kernel(
    const ushort* __restrict__ feath, const ushort* __restrict__ wxt,
    const float* __restrict__ bx, float* __restrict__ out) {
  const int t = threadIdx.x;
  const int w = t >> 6;
  const int l = t & 63;
  const int row0 = blockIdx.x * 16;
  const int lr = l & 15;
  const int lk = (l >> 4) * 8;
  const int col0 = w * 64;

  f32x4 acc[4] = {f32x4{0.f, 0.f, 0.f, 0.f}, f32x4{0.f, 0.f, 0.f, 0.f},
                  f32x4{0.f, 0.f, 0.f, 0.f}, f32x4{0.f, 0.f, 0.f, 0.f}};
  const ushort* Abase = feath + (size_t)(row0 + lr) * DIN + lk;
#pragma unroll
  for (int kk = 0; kk < 4; ++kk) {
    const bf16x8 a = *(const bf16x8*)(Abase + kk * 32);
#pragma unroll
    for (int ct = 0; ct < 4; ++ct) {
      const bf16x8 b =
          *(const bf16x8*)(wxt + (size_t)(col0 + ct * 16 + lr) * DIN + kk * 32 + lk);
      acc[ct] = __builtin_amdgcn_mfma_f32_16x16x32_bf16(a, b, acc[ct], 0, 0, 0);
    }
  }
  const int crow0 = row0 + (l >> 4) * 4;
#pragma unroll
  for (int ct = 0; ct < 4; ++ct) {
    const int c = col0 + ct * 16 + lr;
    const float bv = bx[c];
#pragma unroll
    for (int r = 0; r < 4; ++r)
      out[(size_t)(crow0 + r) * DOUT + c] = acc[ct][r] + bv;
  }
}

extern "C" void kernel_launch(void* const* d_in, const int* in_sizes, int n_in,
                              void* d_out, int out_size, void* d_ws, size_t ws_size,
                              hipStream_t stream) {
  const float* x   = (const float*)d_in[0];
  const int*   row = (const int*)d_in[1];
  const int*   col = (const int*)d_in[2];
  const float* adj = (const float*)d_in[3];
  const float* Wr  = (const float*)d_in[4];
  const float* Wc  = (const float*)d_in[5];
  const float* Wx  = (const float*)d_in[6];
  const float* bx  = (const float*)d_in[7];
  float* out = (float*)d_out;

  const int n = in_sizes[0] / DIN;   // 50000
  const int E = in_sizes[1];         // 1600000
  const int nb = (n + 63) >> BSH;    // 782 buckets
  const int npart = (E + PB_CHUNK - 1) / PB_CHUNK;   // 196
  const int nproj = (n + 31) / 32;                   // 1563

  // Workspace layout
  int* w4 = (int*)d_ws;
  float* a_row   = (float*)w4;  w4 += (size_t)n * DA;          // 6.4 MB
  ushort* feath  = (ushort*)w4; w4 += (size_t)n * DIN / 2;     // 12.8 MB
  ushort* a_colh = (ushort*)w4; w4 += (size_t)n * DA / 2;      // 3.2 MB
  uint*   xh     = (uint*)w4;   w4 += (size_t)n * DIN / 2;     // 12.8 MB
  int2*   ibuf   = (int2*)w4;   w4 += (size_t)nb * BCAP * 2;   // 16.0 MB
  int*    bcursor= w4;          w4 += (size_t)nb * CSTRIDE;    // 0.1 MB
  ushort* wxt    = (ushort*)w4;                                // 64 KB
  // total ~= 51.4 MB

  wconv_kernel<<<17, 256, 0, stream>>>(Wx, wxt, bcursor, nb);
  part_kernel<<<npart, 512, 0, stream>>>(row, col, adj, bcursor, ibuf, nb, E);
  proj_kernel<<<nproj, 512, 0, stream>>>(
      x, Wr, Wc, a_row, a_colh, (ushort*)xh, n);
  node_kernel<<<nb, 512, 0, stream>>>(
      (const uint*)xh, a_row, a_colh, bcursor, ibuf, feath, n);
  gemm_kernel<<<n / 16, 256, 0, stream>>>(feath, wxt, bx, out);
}

// Round 10
// 249.295 us; speedup vs baseline: 1.0836x; 1.0836x over previous
//
#include <hip/hip_runtime.h>

// ComHG graph attention: N=50000, E=1.6M, DIN=128, DOUT=256, DA=32
// Round 16 (merge R9's sorted part back INTO super + compress ibuf):
//  - R9 lesson: LDS-sorted part was right, but splitting super lost the
//    part/proj overlap (+15us). This round: super = part' UNION proj again.
//  - part': LDS counting sort of each 8192-edge chunk, then COALESCED
//    run-writes. ibuf compressed to split arrays: ibufk u32
//    (rowlocal<<16|col) + ibufa ushort (adj bf16): 12MB vs 16MB, and LDS
//    staging 57.4KB (sek u32 + sea ushort) -> super caps at 2 blocks/CU
//    (proj = 16 waves/CU, ample for streaming+MFMA).
//  - adj->bf16: error budget 0.0625 -> ~0.08 vs threshold 0.205 (adj sits
//    next to already-bf16 feat/x/a_col roundings).
//  - node: reads ibufk/ibufa (-4MB), eL split col u32 + adj ushort (-7KB
//    LDS -> 22KB, still 4 blocks/CU); spk packs (adjh<<16|col).
//  - wconv, proj body, gemm verbatim R7 (controls).
// Pipeline (4 dispatches):
//   K0 wconv: Wxt(bf16 [n][k]); wrct(bf16 [64][128]); bcursor[b]=b*BCAP
//   K1 super: [part'] hist -> scan -> reserve -> LDS sort -> coalesced
//             ibufk/ibufa run-writes   [proj] MFMA projections + xh=bf16(x)
//   K2 node:  per-bucket LDS sort + fused logits/softmax/SpMM -> feath(bf16)
//   K3 gemm:  out = feath @ Wxt^T + b_x   (MFMA bf16, f32 acc)
// (global-max shift dropped: cancels in p/deg up to 1e-15 eps)

#define DIN   128
#define DOUT  256
#define DA    32
#define SLOPE 0.2f
#define RSQRT_DA 0.17677669529663687f   // 1/sqrt(32)
#define BSH   6                         // 64 nodes per bucket
#define BCAP  2560                      // bucket capacity: mean 2048, +11sigma
#define CSTRIDE 32                      // bcursor padding: 1 counter / 128B
#define NBMAX 800                       // LDS sizing; nb = ceil(n/64) = 782
#define PB_CHUNK 8192
#define NU    5                         // BCAP/512 staging iters (node)

typedef unsigned int uint;
typedef unsigned short ushort;
typedef __attribute__((ext_vector_type(8))) short bf16x8;
typedef __attribute__((ext_vector_type(4))) float f32x4;

static __device__ __forceinline__ ushort f2bf(float f) {
  const uint u = __float_as_uint(f);
  return (ushort)((u + 0x7fffu + ((u >> 16) & 1u)) >> 16);
}

// ---------------- K0: weight prep + bucket cursor init ----------------
// blocks 0..15 : Wx (f32 [k][n=256]) -> Wxt (bf16 [n][k])
// blocks 16..19: [Wr|Wc] (f32 [k][32] each) -> wrct (bf16 [c=64][k=128])
// block  20    : bcursor[b*CSTRIDE] = b*BCAP
__global__ __launch_bounds__(256) void wconv_kernel(
    const float* __restrict__ Wx, ushort* __restrict__ wxt,
    const float* __restrict__ Wr, const float* __restrict__ Wc,
    ushort* __restrict__ wrct, int* __restrict__ bcursor, int nb) {
  __shared__ ushort s[16][DIN];
  const int t = threadIdx.x;
  const int b = blockIdx.x;
  if (b < 16) {
    const int c0 = b * 16;
#pragma unroll
    for (int u = 0; u < 8; ++u) {
      const int k = u * 16 + (t >> 4);
      s[t & 15][k] = f2bf(Wx[(size_t)k * DOUT + c0 + (t & 15)]);
    }
    __syncthreads();
    const int c = t >> 4;          // 0..15
    const int kk = (t & 15) * 8;   // 0..120
    *(uint4*)(wxt + (size_t)(c0 + c) * DIN + kk) = *(const uint4*)&s[c][kk];
  } else if (b < 20) {
    const int c = (b - 16) * 16 + (t >> 4);   // 0..63
    const int k0 = (t & 15) * 8;              // 0..120
    const float* src = (c < DA) ? (Wr + c) : (Wc + (c - DA));
    ushort h[8];
#pragma unroll
    for (int j = 0; j < 8; ++j) h[j] = f2bf(src[(size_t)(k0 + j) * DA]);
    uint4 v;
    v.x = (uint)h[0] | ((uint)h[1] << 16);
    v.y = (uint)h[2] | ((uint)h[3] << 16);
    v.z = (uint)h[4] | ((uint)h[5] << 16);
    v.w = (uint)h[6] | ((uint)h[7] << 16);
    *(uint4*)(wrct + (size_t)c * DIN + k0) = v;
  } else {
    for (int i = t; i < nb; i += 256) bcursor[i * CSTRIDE] = i * BCAP;
  }
}

// ---------------- K1: super = part' UNION proj ----------------
// blocks [0, npart): LDS counting sort -> coalesced bucket run-writes.
// blocks [npart, npart+nproj): MFMA projections, 32 nodes/block.
__global__ __launch_bounds__(512) void super_kernel(
    const float* __restrict__ x, const ushort* __restrict__ wrct,
    float* __restrict__ a_row, ushort* __restrict__ a_colh,
    ushort* __restrict__ xh,
    const int* __restrict__ row, const int* __restrict__ col,
    const float* __restrict__ adj, int* __restrict__ bcursor,
    uint* __restrict__ ibufk, ushort* __restrict__ ibufa,
    int nb, int E, int npart, int n) {
  __shared__ union {
    struct {
      uint   sek[PB_CHUNK];              // 32 KB sorted keys
      ushort sea[PB_CHUNK];              // 16 KB sorted adj (bf16)
      int hist[NBMAX];                   // 3.2 KB
      int lscan[NBMAX];                  // 3.2 KB
      int gbase[NBMAX];                  // 3.2 KB
    } p;                                 // 57.4 KB
    ushort xb[32][136];                  // proj: 8.7 KB
  } sh;
  const int t = threadIdx.x;

  if ((int)blockIdx.x < npart) {
    // ---- part': sort-then-write ----
    int* hist = sh.p.hist;
    int* lscan = sh.p.lscan;
    int* gbase = sh.p.gbase;
    const int e0 = blockIdx.x * PB_CHUNK;
    int myrow[PB_CHUNK / 512];
    for (int b = t; b < nb; b += 512) hist[b] = 0;
    __syncthreads();
#pragma unroll
    for (int u = 0; u < PB_CHUNK / 512; ++u) {
      const int e = e0 + u * 512 + t;
      myrow[u] = (e < E) ? row[e] : -1;
      if (myrow[u] >= 0) atomicAdd(&hist[myrow[u] >> BSH], 1);
    }
    __syncthreads();
    if (t < 64) {                      // single-wave chunked exclusive scan
      int running = 0;
      for (int base = 0; base < nb; base += 64) {
        const int idx = base + t;
        const int v = (idx < nb) ? hist[idx] : 0;
        int inc = v;
#pragma unroll
        for (int ofs = 1; ofs < 64; ofs <<= 1) {
          const int o = __shfl_up(inc, ofs, 64);
          if (t >= ofs) inc += o;
        }
        if (idx < nb) lscan[idx] = running + inc - v;
        running += __shfl(inc, 63, 64);
      }
    }
    __syncthreads();
    for (int b = t; b < nb; b += 512) {
      const int c = hist[b];
      gbase[b] = c ? atomicAdd(&bcursor[b * CSTRIDE], c) : 0;
      hist[b] = 0;                     // reuse as rank counter
    }
    __syncthreads();
#pragma unroll
    for (int u = 0; u < PB_CHUNK / 512; ++u) {
      const int e = e0 + u * 512 + t;
      if (myrow[u] >= 0) {
        const int b = myrow[u] >> BSH;
        const int pos = lscan[b] + atomicAdd(&hist[b], 1);
        sh.p.sek[pos] = ((uint)b << 22) | ((uint)(myrow[u] & 63) << 16) |
                        (uint)col[e];
        sh.p.sea[pos] = f2bf(adj[e]);
      }
    }
    __syncthreads();
    const int cnt_total = min(PB_CHUNK, E - e0);
#pragma unroll
    for (int u = 0; u < PB_CHUNK / 512; ++u) {
      const int el = u * 512 + t;
      if (el < cnt_total) {
        const uint k = sh.p.sek[el];
        const int b = (int)(k >> 22);
        const int gpos = gbase[b] + (el - lscan[b]);
        ibufk[gpos] = k & 0x3fffffu;     // rowlocal<<16 | col
        ibufa[gpos] = sh.p.sea[el];
      }
    }
    return;
  }

  // ---- proj: 32 nodes per block ----
  const int pb = blockIdx.x - npart;
  const int node0 = pb * 32;
  const float4* xg = (const float4*)(x + (size_t)node0 * DIN);
  if (node0 + 32 <= n) {
#pragma unroll
    for (int u = 0; u < 2; ++u) {
      const int f = t + u * 512;               // 0..1023 = node*32 + c4
      const float4 v = xg[f];
      ushort4 h;
      h.x = f2bf(v.x); h.y = f2bf(v.y); h.z = f2bf(v.z); h.w = f2bf(v.w);
      *(ushort4*)&sh.xb[f >> 5][(f & 31) * 4] = h;
      ((ushort4*)(xh + (size_t)node0 * DIN))[f] = h;
    }
  } else {                                     // guarded tail block
#pragma unroll
    for (int u = 0; u < 2; ++u) {
      const int f = t + u * 512;
      const int nd = node0 + (f >> 5);
      float4 v;
      if (nd < n) v = xg[f];
      else { v.x = 0.f; v.y = 0.f; v.z = 0.f; v.w = 0.f; }
      ushort4 h;
      h.x = f2bf(v.x); h.y = f2bf(v.y); h.z = f2bf(v.z); h.w = f2bf(v.w);
      *(ushort4*)&sh.xb[f >> 5][(f & 31) * 4] = h;
      if (nd < n) ((ushort4*)(xh + (size_t)node0 * DIN))[f] = h;
    }
  }
  __syncthreads();

  const int w = t >> 6;
  const int l = t & 63;
  const int lr = l & 15;
  const int lk = (l >> 4) * 8;
  const int h2 = w & 1;          // node half (16 nodes each)
  const int q = w >> 1;          // col quarter (16 of 64 cols)
  f32x4 acc = {0.f, 0.f, 0.f, 0.f};
#pragma unroll
  for (int kk = 0; kk < 4; ++kk) {
    const bf16x8 a = *(const bf16x8*)&sh.xb[h2 * 16 + lr][kk * 32 + lk];
    const bf16x8 bb =
        *(const bf16x8*)(wrct + (size_t)(q * 16 + lr) * DIN + kk * 32 + lk);
    acc = __builtin_amdgcn_mfma_f32_16x16x32_bf16(a, bb, acc, 0, 0, 0);
  }
  const int colq = q * 16 + lr;  // 0..63 of [a_row | a_col]
  const int r0 = (l >> 4) * 4;
#pragma unroll
  for (int r = 0; r < 4; ++r) {
    const int node = node0 + h2 * 16 + r0 + r;
    if (node < n) {
      if (colq < DA)
        a_row[(size_t)node * DA + colq] = acc[r] * RSQRT_DA;
      else
        a_colh[(size_t)node * DA + (colq - DA)] = f2bf(acc[r]);
    }
  }
}

// ---------------- K2: per-bucket sort + fused logits/softmax/SpMM ----------
// Block = one 64-node bucket, 512 thr (8 waves). Stage bucket edges to regs,
// LDS hist + single-wave shfl scan + scatter -> sorted eLk/eLa, then
// 2-nodes-per-wave pair loop (4 pairs/wave). spk packs (adjh<<16 | col).
#define NODE_BODY(J)                                                    \
  {                                                                     \
    const uint kv = spk[w][half][(J)];                                  \
    const float pv = sp[w][half][(J)];                                  \
    const uint2 xv = xh2[(size_t)(kv & 0xffffu) * 32 + la];             \
    const float av = __uint_as_float(kv & 0xffff0000u);                 \
    const float f0 = __uint_as_float(xv.x << 16);                       \
    const float f1 = __uint_as_float(xv.x & 0xffff0000u);               \
    const float f2 = __uint_as_float(xv.y << 16);                       \
    const float f3 = __uint_as_float(xv.y & 0xffff0000u);               \
    aa0 += av * f0; aa1 += av * f1; aa2 += av * f2; aa3 += av * f3;     \
    ap0 += pv * f0; ap1 += pv * f1; ap2 += pv * f2; ap3 += pv * f3;     \
    deg += pv;                                                          \
  }

__global__ __launch_bounds__(512) void node_kernel(
    const uint* __restrict__ xh, const float* __restrict__ a_row,
    const ushort* __restrict__ a_colh, const int* __restrict__ bcursor,
    const uint* __restrict__ ibufk, const ushort* __restrict__ ibufa,
    ushort* __restrict__ feath, int n) {
  __shared__ uint   eLk[BCAP];        // 10.2 KB sorted col
  __shared__ ushort eLa[BCAP];        // 5.1 KB sorted adj (bf16)
  __shared__ int    cnt[64];
  __shared__ int    excl[65];
  __shared__ uint   spk[8][2][32];    // (adjh<<16 | col)
  __shared__ float  sp[8][2][32];
  __shared__ float  s_ar[8][2][32];
  const int t = threadIdx.x;
  const int b = blockIdx.x;
  const int node0 = b << BSH;
  const int estart = b * BCAP;
  const int ecnt = bcursor[b * CSTRIDE] - estart;

  if (t < 64) cnt[t] = 0;
  __syncthreads();
  uint   myk[NU];
  ushort mya[NU];
#pragma unroll
  for (int u = 0; u < NU; ++u) {
    const int e = u * 512 + t;
    if (e < ecnt) {
      myk[u] = ibufk[estart + e];
      mya[u] = ibufa[estart + e];
      atomicAdd(&cnt[myk[u] >> 16], 1);
    }
  }
  __syncthreads();
  if (t < 64) {                        // single-wave inclusive scan (shfl)
    const int v = cnt[t];
    int inc = v;
#pragma unroll
    for (int ofs = 1; ofs < 64; ofs <<= 1) {
      const int o = __shfl_up(inc, ofs, 64);
      if (t >= ofs) inc += o;
    }
    excl[t] = inc - v;                 // exclusive
    if (t == 63) excl[64] = inc;       // == ecnt
    cnt[t] = 0;                        // reuse as rank counter
  }
  __syncthreads();
#pragma unroll
  for (int u = 0; u < NU; ++u) {
    const int e = u * 512 + t;
    if (e < ecnt) {
      const int rl = (int)(myk[u] >> 16);
      const int pos = excl[rl] + atomicAdd(&cnt[rl], 1);
      eLk[pos] = myk[u] & 0xffffu;
      eLa[pos] = mya[u];
    }
  }
  __syncthreads();

  const int w = t >> 6;
  const int lane = t & 63;
  const int half = lane >> 5;
  const int la = lane & 31;
  const uint2* xh2 = (const uint2*)xh;

  for (int pp = 0; pp < 4; ++pp) {          // 4 pairs per wave (8 waves)
    const int rl0 = (pp * 8 + w) * 2;       // local row of first node in pair
    const int i = node0 + rl0 + half;
    const int o0 = excl[rl0];
    const int o1 = excl[rl0 + 1];
    const int o2 = excl[rl0 + 2];
    const int d0 = o1 - o0, d1 = o2 - o1;
    const int myoff = half ? o1 : o0;
    const int myd = half ? d1 : d0;
    const int dmax = max(d0, d1);           // wave-uniform
    s_ar[w][half][la] = (i < n) ? a_row[(size_t)i * DA + la] : 0.f;

    float aa0 = 0.f, aa1 = 0.f, aa2 = 0.f, aa3 = 0.f;
    float ap0 = 0.f, ap1 = 0.f, ap2 = 0.f, ap3 = 0.f;
    float deg = 0.f;

    for (int base = 0; base < dmax; base += 32) {
      const int m = myd - base;             // active count for this half
      if (la < m) {
        const uint c = eLk[myoff + base + la];
        const uint ah = (uint)eLa[myoff + base + la];
        spk[w][half][la] = (ah << 16) | c;
        const uint4* ac = (const uint4*)(a_colh + (size_t)c * DA);
        const float* ar = s_ar[w][half];
        float dot = 0.f;
#pragma unroll
        for (int k = 0; k < 4; ++k) {
          const uint4 q = ac[k];
          const float* a = ar + k * 8;
          dot += __uint_as_float(q.x << 16) * a[0] +
                 __uint_as_float(q.x & 0xffff0000u) * a[1] +
                 __uint_as_float(q.y << 16) * a[2] +
                 __uint_as_float(q.y & 0xffff0000u) * a[3] +
                 __uint_as_float(q.z << 16) * a[4] +
                 __uint_as_float(q.z & 0xffff0000u) * a[5] +
                 __uint_as_float(q.w << 16) * a[6] +
                 __uint_as_float(q.w & 0xffff0000u) * a[7];
        }
        const float lg = (dot >= 0.f) ? dot : SLOPE * dot;
        sp[w][half][la] = __expf(lg);       // same-wave RAW, no barrier
      } else {
        spk[w][half][la] = 0u;              // col 0, adj 0 -> harmless
        sp[w][half][la] = 0.f;
      }
      const int mmax = min(32, dmax - base);
      int j = 0;
      for (; j + 8 <= mmax; j += 8) {
#pragma unroll
        for (int u = 0; u < 8; ++u) NODE_BODY(j + u)
      }
      for (; j < mmax; ++j) NODE_BODY(j)
    }
    if (i < n) {
      const float inv = 0.5f / (deg + 1e-15f);
      ushort4 h;
      h.x = f2bf(0.5f * aa0 + inv * ap0);
      h.y = f2bf(0.5f * aa1 + inv * ap1);
      h.z = f2bf(0.5f * aa2 + inv * ap2);
      h.w = f2bf(0.5f * aa3 + inv * ap3);
      *(ushort4*)(feath + (size_t)i * DIN + la * 4) = h;
    }
  }
}

// ---------------- K3: MFMA GEMM out = feath @ Wxt^T + b ----------------
__global__ __launch_bounds__(256) void gemm_kernel(
    const ushort* __restrict__ feath, const ushort* __restrict__ wxt,
    const float* __restrict__ bx, float* __restrict__ out) {
  const int t = threadIdx.x;
  const int w = t >> 6;
  const int l = t & 63;
  const int row0 = blockIdx.x * 16;
  const int lr = l & 15;
  const int lk = (l >> 4) * 8;
  const int col0 = w * 64;

  f32x4 acc[4] = {f32x4{0.f, 0.f, 0.f, 0.f}, f32x4{0.f, 0.f, 0.f, 0.f},
                  f32x4{0.f, 0.f, 0.f, 0.f}, f32x4{0.f, 0.f, 0.f, 0.f}};
  const ushort* Abase = feath + (size_t)(row0 + lr) * DIN + lk;
#pragma unroll
  for (int kk = 0; kk < 4; ++kk) {
    const bf16x8 a = *(const bf16x8*)(Abase + kk * 32);
#pragma unroll
    for (int ct = 0; ct < 4; ++ct) {
      const bf16x8 b =
          *(const bf16x8*)(wxt + (size_t)(col0 + ct * 16 + lr) * DIN + kk * 32 + lk);
      acc[ct] = __builtin_amdgcn_mfma_f32_16x16x32_bf16(a, b, acc[ct], 0, 0, 0);
    }
  }
  const int crow0 = row0 + (l >> 4) * 4;
#pragma unroll
  for (int ct = 0; ct < 4; ++ct) {
    const int c = col0 + ct * 16 + lr;
    const float bv = bx[c];
#pragma unroll
    for (int r = 0; r < 4; ++r)
      out[(size_t)(crow0 + r) * DOUT + c] = acc[ct][r] + bv;
  }
}

extern "C" void kernel_launch(void* const* d_in, const int* in_sizes, int n_in,
                              void* d_out, int out_size, void* d_ws, size_t ws_size,
                              hipStream_t stream) {
  const float* x   = (const float*)d_in[0];
  const int*   row = (const int*)d_in[1];
  const int*   col = (const int*)d_in[2];
  const float* adj = (const float*)d_in[3];
  const float* Wr  = (const float*)d_in[4];
  const float* Wc  = (const float*)d_in[5];
  const float* Wx  = (const float*)d_in[6];
  const float* bx  = (const float*)d_in[7];
  float* out = (float*)d_out;

  const int n = in_sizes[0] / DIN;   // 50000
  const int E = in_sizes[1];         // 1600000
  const int nb = (n + 63) >> BSH;    // 782 buckets
  const int npart = (E + PB_CHUNK - 1) / PB_CHUNK;   // 196
  const int nproj = (n + 31) / 32;                   // 1563

  // Workspace layout
  int* w4 = (int*)d_ws;
  float* a_row   = (float*)w4;  w4 += (size_t)n * DA;          // 6.4 MB
  ushort* feath  = (ushort*)w4; w4 += (size_t)n * DIN / 2;     // 12.8 MB
  ushort* a_colh = (ushort*)w4; w4 += (size_t)n * DA / 2;      // 3.2 MB
  uint*   xh     = (uint*)w4;   w4 += (size_t)n * DIN / 2;     // 12.8 MB
  uint*   ibufk  = (uint*)w4;   w4 += (size_t)nb * BCAP;       // 8.0 MB
  ushort* ibufa  = (ushort*)w4; w4 += (size_t)nb * BCAP / 2;   // 4.0 MB
  int*    bcursor= w4;          w4 += (size_t)nb * CSTRIDE;    // 0.1 MB
  ushort* wxt    = (ushort*)w4; w4 += (size_t)DOUT * DIN / 2;  // 64 KB
  ushort* wrct   = (ushort*)w4;                                // 16 KB
  // total ~= 47.4 MB

  wconv_kernel<<<21, 256, 0, stream>>>(Wx, wxt, Wr, Wc, wrct, bcursor, nb);
  super_kernel<<<npart + nproj, 512, 0, stream>>>(
      x, wrct, a_row, a_colh, (ushort*)xh, row, col, adj, bcursor,
      ibufk, ibufa, nb, E, npart, n);
  node_kernel<<<nb, 512, 0, stream>>>(
      (const uint*)xh, a_row, a_colh, bcursor, ibufk, ibufa, feath, n);
  gemm_kernel<<<n / 16, 256, 0, stream>>>(feath, wxt, bx, out);
}